// Round 1
// baseline (758.867 us; speedup 1.0000x reference)
//
#include <hip/hip_runtime.h>
#include <stdint.h>
#include <stddef.h>

// ---------- types ----------
typedef __attribute__((ext_vector_type(8))) short     bf16x8;   // 8 bf16 in 4 VGPRs
typedef __attribute__((ext_vector_type(4))) float     f32x4;    // MFMA acc
typedef __attribute__((ext_vector_type(4))) float     f32x4v;
typedef __attribute__((ext_vector_type(4))) int       i32x4;
typedef __attribute__((ext_vector_type(8))) unsigned short u16x8;
typedef __attribute__((ext_vector_type(4))) unsigned short u16x4;

// fp32 -> bf16 round-to-nearest-even (int8 values convert exactly)
__device__ __forceinline__ unsigned short f2bf(float f) {
    union { float f; unsigned u; } v; v.f = f;
    unsigned r = v.u + 0x7FFFu + ((v.u >> 16) & 1u);
    return (unsigned short)(r >> 16);
}

// async global->LDS, 16 bytes/lane. LDS dest = wave-uniform base + lane*16.
__device__ __forceinline__ void gload_lds16(const void* g, void* l) {
    __builtin_amdgcn_global_load_lds(
        (const __attribute__((address_space(1))) void*)(g),
        (__attribute__((address_space(3))) void*)(l), 16, 0, 0);
}

// ---------- convert kernels (memory-bound, vectorized 16B loads / 16B stores) ----------
__global__ void cvt_x_kernel(const float* __restrict__ x, unsigned short* __restrict__ o, int n8) {
    int i = blockIdx.x * blockDim.x + threadIdx.x;
    int stride = gridDim.x * blockDim.x;
    for (; i < n8; i += stride) {
        f32x4v a = ((const f32x4v*)x)[2 * (size_t)i];
        f32x4v b = ((const f32x4v*)x)[2 * (size_t)i + 1];
        u16x8 r;
        r[0] = f2bf(a[0]); r[1] = f2bf(a[1]); r[2] = f2bf(a[2]); r[3] = f2bf(a[3]);
        r[4] = f2bf(b[0]); r[5] = f2bf(b[1]); r[6] = f2bf(b[2]); r[7] = f2bf(b[3]);
        ((u16x8*)o)[i] = r;
    }
}

__global__ void cvt_w_kernel(const int* __restrict__ w, unsigned short* __restrict__ o, int n8) {
    int i = blockIdx.x * blockDim.x + threadIdx.x;
    int stride = gridDim.x * blockDim.x;
    for (; i < n8; i += stride) {
        i32x4 a = ((const i32x4*)w)[2 * (size_t)i];
        i32x4 b = ((const i32x4*)w)[2 * (size_t)i + 1];
        u16x8 r;
        r[0] = f2bf((float)a[0]); r[1] = f2bf((float)a[1]);
        r[2] = f2bf((float)a[2]); r[3] = f2bf((float)a[3]);
        r[4] = f2bf((float)b[0]); r[5] = f2bf((float)b[1]);
        r[6] = f2bf((float)b[2]); r[7] = f2bf((float)b[3]);
        ((u16x8*)o)[i] = r;
    }
}

// ---------- GEMM: C[m][n] = (sum_k A[m][k]*W[n][k]) * scale + bias[n] ----------
// 128x128 tile, BK=64, 256 threads = 4 waves in 2x2, each wave owns 64x64.
// Both A and W are K-contiguous (W stored [N][K]) -> identical staging/frag paths.
#define BM 128
#define BN 128
#define BK 64

__global__ __launch_bounds__(256, 2) void gemm_bt(
    const unsigned short* __restrict__ A,   // [M][K] bf16
    const unsigned short* __restrict__ Bw,  // [N][K] bf16
    const float* __restrict__ scale_p,
    const float* __restrict__ bias,
    float* __restrict__ C,
    int M, int N, int K)
{
    __shared__ unsigned short As[BM * BK];  // 16 KB, row-major [128][64]
    __shared__ unsigned short Bs[BN * BK];  // 16 KB

    const int t    = threadIdx.x;
    const int lane = t & 63;
    const int w    = t >> 6;          // wave 0..3
    const int wm   = w >> 1;          // wave row (0..1)
    const int wn   = w & 1;           // wave col (0..1)

    // bijective XCD swizzle (grid % 8 == 0 here)
    int nwg = gridDim.x;
    int bid = blockIdx.x;
    int swz = (nwg % 8 == 0) ? ((bid & 7) * (nwg >> 3) + (bid >> 3)) : bid;
    const int ntn = N / BN;
    const int tm = swz / ntn;
    const int tn = swz % ntn;
    const int row0 = tm * BM;
    const int col0 = tn * BN;

    // staging map: round i, thread t -> tile row i*32 + t/8, elem col (t%8)*8 (16B chunk)
    const int sr = t >> 3;            // 0..31
    const int sc = (t & 7) * 8;       // elem offset in row

    f32x4 acc[4][4] = {};

    const size_t ldK = (size_t)K;
    const int lr = lane & 15;
    const int lkbase = (lane >> 4) * 8;

    for (int kt = 0; kt < K; kt += BK) {
        // ---- stage A (4 x 16B/thread) and B (4 x 16B/thread), linear LDS ----
#pragma unroll
        for (int i = 0; i < 4; ++i) {
            const unsigned short* ga = A + (size_t)(row0 + i * 32 + sr) * ldK + kt + sc;
            gload_lds16(ga, &As[(i * 256 + t) * 8]);
        }
#pragma unroll
        for (int i = 0; i < 4; ++i) {
            const unsigned short* gb = Bw + (size_t)(col0 + i * 32 + sr) * ldK + kt + sc;
            gload_lds16(gb, &Bs[(i * 256 + t) * 8]);
        }
        __syncthreads();   // compiler drains vmcnt(0) before s_barrier

        // ---- compute: 2 K-substeps of 32, 16 MFMA each ----
#pragma unroll
        for (int ks = 0; ks < 2; ++ks) {
            const int lk = lkbase + ks * 32;
            bf16x8 af[4], bfr[4];
#pragma unroll
            for (int m = 0; m < 4; ++m)
                af[m] = *(const bf16x8*)&As[(wm * 64 + m * 16 + lr) * BK + lk];
#pragma unroll
            for (int n = 0; n < 4; ++n)
                bfr[n] = *(const bf16x8*)&Bs[(wn * 64 + n * 16 + lr) * BK + lk];
#pragma unroll
            for (int m = 0; m < 4; ++m)
#pragma unroll
                for (int n = 0; n < 4; ++n)
                    acc[m][n] = __builtin_amdgcn_mfma_f32_16x16x32_bf16(
                        af[m], bfr[n], acc[m][n], 0, 0, 0);
        }
        __syncthreads();
    }

    // ---- epilogue: C = acc*scale + bias; C/D layout col=lane&15, row=(lane>>4)*4+j ----
    const float s  = scale_p[0];
    const int  lq4 = (lane >> 4) * 4;
#pragma unroll
    for (int m = 0; m < 4; ++m) {
#pragma unroll
        for (int n = 0; n < 4; ++n) {
            const int col = col0 + wn * 64 + n * 16 + lr;
            const float bv = bias[col];
#pragma unroll
            for (int j = 0; j < 4; ++j) {
                const int row = row0 + wm * 64 + m * 16 + lq4 + j;
                C[(size_t)row * N + col] = acc[m][n][j] * s + bv;
            }
        }
    }
}

// ---------- fallback: fused convert-in-staging GEMM (used only if ws too small) ----------
__global__ __launch_bounds__(256, 2) void gemm_fused(
    const float* __restrict__ A,      // [M][K] fp32
    const int* __restrict__ Bw,       // [N][K] int32 (int8 values)
    const float* __restrict__ scale_p,
    const float* __restrict__ bias,
    float* __restrict__ C,
    int M, int N, int K)
{
    __shared__ unsigned short As[BM * BK];
    __shared__ unsigned short Bs[BN * BK];

    const int t    = threadIdx.x;
    const int lane = t & 63;
    const int w    = t >> 6;
    const int wm   = w >> 1;
    const int wn   = w & 1;

    int nwg = gridDim.x;
    int bid = blockIdx.x;
    int swz = (nwg % 8 == 0) ? ((bid & 7) * (nwg >> 3) + (bid >> 3)) : bid;
    const int ntn = N / BN;
    const int tm = swz / ntn;
    const int tn = swz % ntn;
    const int row0 = tm * BM;
    const int col0 = tn * BN;

    f32x4 acc[4][4] = {};
    const int lr = lane & 15;
    const int lkbase = (lane >> 4) * 8;

    for (int kt = 0; kt < K; kt += BK) {
#pragma unroll
        for (int i = 0; i < 8; ++i) {   // 8 rounds x 16 rows
            const int r = i * 16 + (t >> 4);
            const int c = (t & 15) * 4;
            f32x4v v = *(const f32x4v*)&A[(size_t)(row0 + r) * K + kt + c];
            u16x4 o; o[0] = f2bf(v[0]); o[1] = f2bf(v[1]); o[2] = f2bf(v[2]); o[3] = f2bf(v[3]);
            *(u16x4*)&As[r * BK + c] = o;
        }
#pragma unroll
        for (int i = 0; i < 8; ++i) {
            const int r = i * 16 + (t >> 4);
            const int c = (t & 15) * 4;
            i32x4 v = *(const i32x4*)&Bw[(size_t)(col0 + r) * K + kt + c];
            u16x4 o; o[0] = f2bf((float)v[0]); o[1] = f2bf((float)v[1]);
                     o[2] = f2bf((float)v[2]); o[3] = f2bf((float)v[3]);
            *(u16x4*)&Bs[r * BK + c] = o;
        }
        __syncthreads();
#pragma unroll
        for (int ks = 0; ks < 2; ++ks) {
            const int lk = lkbase + ks * 32;
            bf16x8 af[4], bfr[4];
#pragma unroll
            for (int m = 0; m < 4; ++m)
                af[m] = *(const bf16x8*)&As[(wm * 64 + m * 16 + lr) * BK + lk];
#pragma unroll
            for (int n = 0; n < 4; ++n)
                bfr[n] = *(const bf16x8*)&Bs[(wn * 64 + n * 16 + lr) * BK + lk];
#pragma unroll
            for (int m = 0; m < 4; ++m)
#pragma unroll
                for (int n = 0; n < 4; ++n)
                    acc[m][n] = __builtin_amdgcn_mfma_f32_16x16x32_bf16(
                        af[m], bfr[n], acc[m][n], 0, 0, 0);
        }
        __syncthreads();
    }

    const float s  = scale_p[0];
    const int  lq4 = (lane >> 4) * 4;
#pragma unroll
    for (int m = 0; m < 4; ++m) {
#pragma unroll
        for (int n = 0; n < 4; ++n) {
            const int col = col0 + wn * 64 + n * 16 + lr;
            const float bv = bias[col];
#pragma unroll
            for (int j = 0; j < 4; ++j) {
                const int row = row0 + wm * 64 + m * 16 + lq4 + j;
                C[(size_t)row * N + col] = acc[m][n][j] * s + bv;
            }
        }
    }
}

extern "C" void kernel_launch(void* const* d_in, const int* in_sizes, int n_in,
                              void* d_out, int out_size, void* d_ws, size_t ws_size,
                              hipStream_t stream) {
    const float* x     = (const float*)d_in[0];
    const int*   w8    = (const int*)d_in[1];
    const float* scale = (const float*)d_in[2];
    const float* bias  = (const float*)d_in[3];
    float* out = (float*)d_out;

    const int N = in_sizes[3];                    // 16384
    const int K = (int)((long)in_sizes[1] / N);   // 4096
    const int M = (int)((long)in_sizes[0] / K);   // 4096

    const size_t needA = (size_t)M * K * 2;
    const size_t needB = (size_t)N * K * 2;
    const int nblocks = (M / BM) * (N / BN);

    if (ws_size >= needA + needB) {
        unsigned short* Ab = (unsigned short*)d_ws;
        unsigned short* Bb = (unsigned short*)((char*)d_ws + needA);
        cvt_x_kernel<<<2048, 256, 0, stream>>>(x, Ab, M * K / 8);
        cvt_w_kernel<<<2048, 256, 0, stream>>>(w8, Bb, N * K / 8);
        gemm_bt<<<nblocks, 256, 0, stream>>>(Ab, Bb, scale, bias, out, M, N, K);
    } else {
        gemm_fused<<<nblocks, 256, 0, stream>>>(x, w8, scale, bias, out, M, N, K);
    }
}